// Round 2
// baseline (1052.415 us; speedup 1.0000x reference)
//
#include <hip/hip_runtime.h>
#include <cstdint>

// Problem constants (match reference)
#define N_PTS 100000
#define DIN   40
#define DH    30
#define DOUT  10
#define NB    10000
#define NNB   64
#define NR    10
#define EPSF  1e-5f

__device__ __forceinline__ float fast_rcp(float x) {
    // v_rcp_f32 (~1e-7 rel err) + one Newton step -> effectively fp32-exact
    float r = __builtin_amdgcn_rcpf(x);
    r = r * (2.0f - x * r);
    return r;
}

// ---------------------------------------------------------------------------
// Kernel 1: MLP embedding. emb[n][d] = prelu(W2 @ prelu(W1 @ x[n] + b1, a1) + b2, a2)
// One point per thread; weights staged in LDS (broadcast reads).
// ---------------------------------------------------------------------------
__global__ __launch_bounds__(256) void mlp_kernel(
    const float* __restrict__ x,
    const float* __restrict__ W1, const float* __restrict__ b1, const float* __restrict__ a1p,
    const float* __restrict__ W2, const float* __restrict__ b2, const float* __restrict__ a2p,
    float* __restrict__ emb)
{
    __shared__ float sW1[DH * DIN];
    __shared__ float sW2[DOUT * DH];
    __shared__ float sb1[DH];
    __shared__ float sb2[DOUT];
    for (int i = threadIdx.x; i < DH * DIN; i += 256) sW1[i] = W1[i];
    for (int i = threadIdx.x; i < DOUT * DH; i += 256) sW2[i] = W2[i];
    if (threadIdx.x < DH)   sb1[threadIdx.x] = b1[threadIdx.x];
    if (threadIdx.x < DOUT) sb2[threadIdx.x] = b2[threadIdx.x];
    const float a1 = a1p[0], a2 = a2p[0];
    __syncthreads();

    const int n = blockIdx.x * 256 + threadIdx.x;
    if (n >= N_PTS) return;

    float xv[DIN];
    const float4* xp = reinterpret_cast<const float4*>(x + (size_t)n * DIN); // 160B rows, 16B aligned
#pragma unroll
    for (int q = 0; q < DIN / 4; ++q) {
        float4 v = xp[q];
        xv[4*q+0] = v.x; xv[4*q+1] = v.y; xv[4*q+2] = v.z; xv[4*q+3] = v.w;
    }

    float h[DH];
#pragma unroll
    for (int i = 0; i < DH; ++i) {
        float acc = sb1[i];
#pragma unroll
        for (int j = 0; j < DIN; ++j) acc = fmaf(xv[j], sW1[i * DIN + j], acc);
        h[i] = acc > 0.0f ? acc : a1 * acc;
    }

    float* eo = emb + (size_t)n * DOUT;
#pragma unroll
    for (int d = 0; d < DOUT; ++d) {
        float acc = sb2[d];
#pragma unroll
        for (int i = 0; i < DH; ++i) acc = fmaf(h[i], sW2[d * DH + i], acc);
        eo[d] = acc > 0.0f ? acc : a2 * acc;
    }
}

// ---------------------------------------------------------------------------
// Kernel 2: one wave (64 lanes) per batch item. Lane i owns row i of the
// 64x64 kernel matrix (in registers) + its 11-wide RHS row (in registers).
// Gaussian elimination w/o pivoting (SPD), pivot row broadcast via readlane.
// No LDS, no barriers (single-wave block). All register indices static via
// full unroll (constant-bound loops + guards).
//
// __launch_bounds__(64, 1): min 1 wave/EU -> VGPR cap 512. R1 fix: the
// default heuristic allocated 92 VGPRs and spilled ar[64] to scratch
// (3 GB of HBM spill writes, VALUBusy 12.6%). Live set ~100-150 regs must
// stay in the RF; we trade occupancy (1 wave/SIMD) for zero spills.
// ---------------------------------------------------------------------------
__global__ __launch_bounds__(64, 1) void solve_kernel(
    const float* __restrict__ emb,
    const int* __restrict__ bidx,
    const int* __restrict__ bnn,
    const float* __restrict__ tnn_g,
    float* __restrict__ pred,   // [NB][NR]
    float* __restrict__ var,    // [NB]
    float* __restrict__ part)   // [NB][NR] sigma_sq partials
{
    const int b   = blockIdx.x;
    const int tid = threadIdx.x; // 0..63

    // Gather this lane's neighbor embedding (10 floats, 8B-aligned rows)
    const int idx = bnn[b * NNB + tid];
    float xn[DOUT];
    {
        const float2* ep = reinterpret_cast<const float2*>(emb + (size_t)idx * DOUT);
#pragma unroll
        for (int q = 0; q < DOUT / 2; ++q) { float2 v = ep[q]; xn[2*q] = v.x; xn[2*q+1] = v.y; }
    }
    // Center embedding (same for all lanes; broadcast through cache)
    const int bi = bidx[b];
    float xb[DOUT];
#pragma unroll
    for (int d = 0; d < DOUT; ++d) xb[d] = emb[(size_t)bi * DOUT + d];

    float sq = 0.0f, dotb = 0.0f, sqb = 0.0f;
#pragma unroll
    for (int d = 0; d < DOUT; ++d) {
        sq   = fmaf(xn[d], xn[d], sq);
        dotb = fmaf(xb[d], xn[d], dotb);
        sqb  = fmaf(xb[d], xb[d], sqb);
    }
    const float d2c = sqb + sq - 2.0f * dotb;
    const float kc  = __expf(-sqrtf(fmaxf(d2c, 0.0f)));

    // Build row tid of Kplus = exp(-dist) + eps*I, entirely in registers.
    float ar[NNB];
#pragma unroll
    for (int j = 0; j < NNB; ++j) {
        float dj = 0.0f;
#pragma unroll
        for (int d = 0; d < DOUT; ++d) dj = fmaf(__shfl(xn[d], j), xn[d], dj);
        const float sqj = __shfl(sq, j);
        const float d2  = sq + sqj - 2.0f * dj;
        const float kij = __expf(-sqrtf(fmaxf(d2, 0.0f)));
        ar[j] = (j == tid) ? (1.0f + EPSF) : kij;   // exact diag, + jitter
    }

    // RHS row: [targets(10), Kcross] ; keep a copy of targets for sigma_sq
    float tn[NR], rr[NR + 1];
    {
        const float2* tp = reinterpret_cast<const float2*>(tnn_g + (size_t)b * NNB * NR + (size_t)tid * NR);
#pragma unroll
        for (int q = 0; q < NR / 2; ++q) { float2 v = tp[q]; tn[2*q] = v.x; tn[2*q+1] = v.y; }
    }
#pragma unroll
    for (int r = 0; r < NR; ++r) rr[r] = tn[r];
    rr[NR] = kc;

    // Forward elimination. Masked lanes get m=0 -> no-op (no divergence).
#pragma unroll
    for (int k = 0; k < NNB - 1; ++k) {
        const float pd  = __shfl(ar[k], k);       // pivot diag (readlane, k const)
        const float inv = fast_rcp(pd);
        const float m   = (tid > k) ? ar[k] * inv : 0.0f;
#pragma unroll
        for (int j = 0; j < NNB; ++j) {
            if (j > k) ar[j] = fmaf(-m, __shfl(ar[j], k), ar[j]);
        }
#pragma unroll
        for (int r = 0; r <= NR; ++r) rr[r] = fmaf(-m, __shfl(rr[r], k), rr[r]);
    }

    // Back substitution: lane k finalizes its solution row; lanes i<k update.
#pragma unroll
    for (int k = NNB - 1; k >= 0; --k) {
        const float invd = fast_rcp(__shfl(ar[k], k));
        const float m    = (tid < k) ? ar[k] : 0.0f;  // U[tid][k], right of diag
#pragma unroll
        for (int r = 0; r <= NR; ++r) {
            const float xk = __shfl(rr[r], k) * invd;  // solution x[k][r]
            rr[r] = (tid == k) ? xk : fmaf(-m, xk, rr[r]);
        }
    }

    // Outputs: predictions, variance, sigma_sq partials (wave butterfly reduce)
    float pv[NR], sg[NR];
#pragma unroll
    for (int r = 0; r < NR; ++r) { pv[r] = kc * rr[r]; sg[r] = tn[r] * rr[r]; }
    float vv = kc * rr[NR];
#pragma unroll
    for (int off = 32; off > 0; off >>= 1) {
#pragma unroll
        for (int r = 0; r < NR; ++r) {
            pv[r] += __shfl_xor(pv[r], off);
            sg[r] += __shfl_xor(sg[r], off);
        }
        vv += __shfl_xor(vv, off);
    }
    if (tid == 0) {
#pragma unroll
        for (int r = 0; r < NR; ++r) {
            pred[b * NR + r] = pv[r];
            part[b * NR + r] = sg[r];
        }
        var[b] = 1.0f - vv;
    }
}

// ---------------------------------------------------------------------------
// Kernel 3: deterministic reduction of sigma_sq partials (fixed order, no atomics)
// ---------------------------------------------------------------------------
__global__ __launch_bounds__(256) void reduce_kernel(
    const float* __restrict__ part, float* __restrict__ sig)
{
    float acc[NR];
#pragma unroll
    for (int r = 0; r < NR; ++r) acc[r] = 0.0f;
    for (int b = threadIdx.x; b < NB; b += 256) {
#pragma unroll
        for (int r = 0; r < NR; ++r) acc[r] += part[b * NR + r];
    }
#pragma unroll
    for (int off = 32; off > 0; off >>= 1) {
#pragma unroll
        for (int r = 0; r < NR; ++r) acc[r] += __shfl_xor(acc[r], off);
    }
    __shared__ float s[4][NR];
    const int w = threadIdx.x >> 6, l = threadIdx.x & 63;
    if (l == 0) {
#pragma unroll
        for (int r = 0; r < NR; ++r) s[w][r] = acc[r];
    }
    __syncthreads();
    if (threadIdx.x == 0) {
        const float scale = 1.0f / ((float)NB * (float)NNB);
#pragma unroll
        for (int r = 0; r < NR; ++r)
            sig[r] = (s[0][r] + s[1][r] + s[2][r] + s[3][r]) * scale;
    }
}

// ---------------------------------------------------------------------------
extern "C" void kernel_launch(void* const* d_in, const int* in_sizes, int n_in,
                              void* d_out, int out_size, void* d_ws, size_t ws_size,
                              hipStream_t stream)
{
    const float* x    = (const float*)d_in[0];
    const int*   bidx = (const int*)  d_in[1];
    const int*   bnn  = (const int*)  d_in[2];
    // d_in[3] = batch_targets: unused by the reference computation
    const float* tnn  = (const float*)d_in[4];
    const float* W1   = (const float*)d_in[5];
    const float* b1   = (const float*)d_in[6];
    const float* a1   = (const float*)d_in[7];
    const float* W2   = (const float*)d_in[8];
    const float* b2   = (const float*)d_in[9];
    const float* a2   = (const float*)d_in[10];

    float* out  = (float*)d_out;
    float* pred = out;                 // 100000
    float* var  = out + NB * NR;       // 10000
    float* sig  = out + NB * NR + NB;  // 10

    float* emb  = (float*)d_ws;        // N_PTS*DOUT = 1,000,000 floats (4 MB)
    float* part = emb + (size_t)N_PTS * DOUT; // NB*NR = 100,000 floats (400 KB)

    mlp_kernel<<<(N_PTS + 255) / 256, 256, 0, stream>>>(x, W1, b1, a1, W2, b2, a2, emb);
    solve_kernel<<<NB, 64, 0, stream>>>(emb, bidx, bnn, tnn, pred, var, part);
    reduce_kernel<<<1, 256, 0, stream>>>(part, sig);
}

// Round 3
// 590.758 us; speedup vs baseline: 1.7815x; 1.7815x over previous
//
#include <hip/hip_runtime.h>
#include <cstdint>

// Problem constants (match reference)
#define N_PTS 100000
#define DIN   40
#define DH    30
#define DOUT  10
#define NB    10000
#define NNB   64
#define NR    10
#define EPSF  1e-5f

__device__ __forceinline__ float fast_rcp(float x) {
    // v_rcp_f32 (~1e-7 rel err) + one Newton step -> effectively fp32-exact
    float r = __builtin_amdgcn_rcpf(x);
    r = r * (2.0f - x * r);
    return r;
}

// ---------------------------------------------------------------------------
// Kernel 1: MLP embedding. One point per thread; weights staged in LDS.
// ---------------------------------------------------------------------------
__global__ __launch_bounds__(256) void mlp_kernel(
    const float* __restrict__ x,
    const float* __restrict__ W1, const float* __restrict__ b1, const float* __restrict__ a1p,
    const float* __restrict__ W2, const float* __restrict__ b2, const float* __restrict__ a2p,
    float* __restrict__ emb)
{
    __shared__ float sW1[DH * DIN];
    __shared__ float sW2[DOUT * DH];
    __shared__ float sb1[DH];
    __shared__ float sb2[DOUT];
    for (int i = threadIdx.x; i < DH * DIN; i += 256) sW1[i] = W1[i];
    for (int i = threadIdx.x; i < DOUT * DH; i += 256) sW2[i] = W2[i];
    if (threadIdx.x < DH)   sb1[threadIdx.x] = b1[threadIdx.x];
    if (threadIdx.x < DOUT) sb2[threadIdx.x] = b2[threadIdx.x];
    const float a1 = a1p[0], a2 = a2p[0];
    __syncthreads();

    const int n = blockIdx.x * 256 + threadIdx.x;
    if (n >= N_PTS) return;

    float xv[DIN];
    const float4* xp = reinterpret_cast<const float4*>(x + (size_t)n * DIN); // 160B rows
#pragma unroll
    for (int q = 0; q < DIN / 4; ++q) {
        float4 v = xp[q];
        xv[4*q+0] = v.x; xv[4*q+1] = v.y; xv[4*q+2] = v.z; xv[4*q+3] = v.w;
    }

    float h[DH];
#pragma unroll
    for (int i = 0; i < DH; ++i) {
        float acc = sb1[i];
#pragma unroll
        for (int j = 0; j < DIN; ++j) acc = fmaf(xv[j], sW1[i * DIN + j], acc);
        h[i] = acc > 0.0f ? acc : a1 * acc;
    }

    float* eo = emb + (size_t)n * DOUT;
#pragma unroll
    for (int d = 0; d < DOUT; ++d) {
        float acc = sb2[d];
#pragma unroll
        for (int i = 0; i < DH; ++i) acc = fmaf(h[i], sW2[d * DH + i], acc);
        eo[d] = acc > 0.0f ? acc : a2 * acc;
    }
}

// ---------------------------------------------------------------------------
// Template-recursive building blocks for the solve: every array index and
// every __shfl lane index is a COMPILE-TIME constant, so ar[]/rr[] live in
// VGPRs (R2 lesson: #pragma unroll on the 63-iter outer loop was NOT honored,
// runtime k forced the arrays into scratch -> 3 GB/launch spill traffic).
// ---------------------------------------------------------------------------

// Build row tid of Kplus = exp(-dist) + eps*I
template<int J>
struct Build {
    static __device__ __forceinline__ void run(float (&ar)[NNB], const float (&xn)[DOUT],
                                               const float sq, const int tid) {
        float dj = 0.0f;
#pragma unroll
        for (int d = 0; d < DOUT; ++d) dj = fmaf(__shfl(xn[d], J), xn[d], dj);
        const float sqj = __shfl(sq, J);
        const float d2  = sq + sqj - 2.0f * dj;
        const float kij = __expf(-sqrtf(fmaxf(d2, 0.0f)));
        ar[J] = (J == tid) ? (1.0f + EPSF) : kij;   // exact diag + jitter
        Build<J + 1>::run(ar, xn, sq, tid);
    }
};
template<>
struct Build<NNB> {
    static __device__ __forceinline__ void run(float (&)[NNB], const float (&)[DOUT],
                                               float, int) {}
};

// Forward elimination step K (masked lanes: m=0 -> arithmetic no-op)
template<int K>
struct Fwd {
    static __device__ __forceinline__ void run(float (&ar)[NNB], float (&rr)[NR + 1],
                                               const int tid) {
        const float inv = fast_rcp(__shfl(ar[K], K));   // readlane, const lane
        const float m   = (tid > K) ? ar[K] * inv : 0.0f;
#pragma unroll
        for (int j = K + 1; j < NNB; ++j)
            ar[j] = fmaf(-m, __shfl(ar[j], K), ar[j]);
#pragma unroll
        for (int r = 0; r <= NR; ++r)
            rr[r] = fmaf(-m, __shfl(rr[r], K), rr[r]);
        Fwd<K + 1>::run(ar, rr, tid);
    }
};
template<>
struct Fwd<NNB - 1> {
    static __device__ __forceinline__ void run(float (&)[NNB], float (&)[NR + 1], int) {}
};

// Back substitution step K (downward): lane K finalizes x[K], lanes i<K update
template<int K>
struct Bwd {
    static __device__ __forceinline__ void run(float (&ar)[NNB], float (&rr)[NR + 1],
                                               const int tid) {
        const float invd = fast_rcp(__shfl(ar[K], K));
        const float m    = (tid < K) ? ar[K] : 0.0f;    // U[tid][K]
#pragma unroll
        for (int r = 0; r <= NR; ++r) {
            const float xk = __shfl(rr[r], K) * invd;   // solution x[K][r]
            rr[r] = (tid == K) ? xk : fmaf(-m, xk, rr[r]);
        }
        Bwd<K - 1>::run(ar, rr, tid);
    }
};
template<>
struct Bwd<-1> {
    static __device__ __forceinline__ void run(float (&)[NNB], float (&)[NR + 1], int) {}
};

// ---------------------------------------------------------------------------
// Kernel 2: one wave per batch item; row of the 64x64 system in registers.
// ---------------------------------------------------------------------------
__global__ __launch_bounds__(64, 1) void solve_kernel(
    const float* __restrict__ emb,
    const int* __restrict__ bidx,
    const int* __restrict__ bnn,
    const float* __restrict__ tnn_g,
    float* __restrict__ pred,   // [NB][NR]
    float* __restrict__ var,    // [NB]
    float* __restrict__ part)   // [NB][NR] sigma_sq partials
{
    const int b   = blockIdx.x;
    const int tid = threadIdx.x; // 0..63

    // Gather this lane's neighbor embedding (10 floats, 8B-aligned rows)
    const int idx = bnn[b * NNB + tid];
    float xn[DOUT];
    {
        const float2* ep = reinterpret_cast<const float2*>(emb + (size_t)idx * DOUT);
#pragma unroll
        for (int q = 0; q < DOUT / 2; ++q) { float2 v = ep[q]; xn[2*q] = v.x; xn[2*q+1] = v.y; }
    }
    // Center embedding (same for all lanes; broadcast through cache)
    const int bi = bidx[b];
    float sq = 0.0f, dotb = 0.0f, sqb = 0.0f;
#pragma unroll
    for (int d = 0; d < DOUT; ++d) {
        const float xbd = emb[(size_t)bi * DOUT + d];
        sq   = fmaf(xn[d], xn[d], sq);
        dotb = fmaf(xbd, xn[d], dotb);
        sqb  = fmaf(xbd, xbd, sqb);
    }
    const float d2c = sqb + sq - 2.0f * dotb;
    const float kc  = __expf(-sqrtf(fmaxf(d2c, 0.0f)));

    // K matrix row (registers, static indices only)
    float ar[NNB];
    Build<0>::run(ar, xn, sq, tid);

    // RHS row: [targets(10), Kcross]; keep targets for sigma_sq
    float tn[NR], rr[NR + 1];
    {
        const float2* tp = reinterpret_cast<const float2*>(
            tnn_g + (size_t)b * NNB * NR + (size_t)tid * NR);
#pragma unroll
        for (int q = 0; q < NR / 2; ++q) { float2 v = tp[q]; tn[2*q] = v.x; tn[2*q+1] = v.y; }
    }
#pragma unroll
    for (int r = 0; r < NR; ++r) rr[r] = tn[r];
    rr[NR] = kc;

    Fwd<0>::run(ar, rr, tid);
    Bwd<NNB - 1>::run(ar, rr, tid);

    // Outputs: predictions, variance, sigma_sq partials (wave butterfly reduce)
    float pv[NR], sg[NR];
#pragma unroll
    for (int r = 0; r < NR; ++r) { pv[r] = kc * rr[r]; sg[r] = tn[r] * rr[r]; }
    float vv = kc * rr[NR];
#pragma unroll
    for (int off = 32; off > 0; off >>= 1) {
#pragma unroll
        for (int r = 0; r < NR; ++r) {
            pv[r] += __shfl_xor(pv[r], off);
            sg[r] += __shfl_xor(sg[r], off);
        }
        vv += __shfl_xor(vv, off);
    }
    if (tid == 0) {
#pragma unroll
        for (int r = 0; r < NR; ++r) {
            pred[b * NR + r] = pv[r];
            part[b * NR + r] = sg[r];
        }
        var[b] = 1.0f - vv;
    }
}

// ---------------------------------------------------------------------------
// Kernel 3: deterministic reduction of sigma_sq partials (fixed order)
// ---------------------------------------------------------------------------
__global__ __launch_bounds__(256) void reduce_kernel(
    const float* __restrict__ part, float* __restrict__ sig)
{
    float acc[NR];
#pragma unroll
    for (int r = 0; r < NR; ++r) acc[r] = 0.0f;
    for (int b = threadIdx.x; b < NB; b += 256) {
#pragma unroll
        for (int r = 0; r < NR; ++r) acc[r] += part[b * NR + r];
    }
#pragma unroll
    for (int off = 32; off > 0; off >>= 1) {
#pragma unroll
        for (int r = 0; r < NR; ++r) acc[r] += __shfl_xor(acc[r], off);
    }
    __shared__ float s[4][NR];
    const int w = threadIdx.x >> 6, l = threadIdx.x & 63;
    if (l == 0) {
#pragma unroll
        for (int r = 0; r < NR; ++r) s[w][r] = acc[r];
    }
    __syncthreads();
    if (threadIdx.x == 0) {
        const float scale = 1.0f / ((float)NB * (float)NNB);
#pragma unroll
        for (int r = 0; r < NR; ++r)
            sig[r] = (s[0][r] + s[1][r] + s[2][r] + s[3][r]) * scale;
    }
}

// ---------------------------------------------------------------------------
extern "C" void kernel_launch(void* const* d_in, const int* in_sizes, int n_in,
                              void* d_out, int out_size, void* d_ws, size_t ws_size,
                              hipStream_t stream)
{
    const float* x    = (const float*)d_in[0];
    const int*   bidx = (const int*)  d_in[1];
    const int*   bnn  = (const int*)  d_in[2];
    // d_in[3] = batch_targets: unused by the reference computation
    const float* tnn  = (const float*)d_in[4];
    const float* W1   = (const float*)d_in[5];
    const float* b1   = (const float*)d_in[6];
    const float* a1   = (const float*)d_in[7];
    const float* W2   = (const float*)d_in[8];
    const float* b2   = (const float*)d_in[9];
    const float* a2   = (const float*)d_in[10];

    float* out  = (float*)d_out;
    float* pred = out;                 // 100000
    float* var  = out + NB * NR;       // 10000
    float* sig  = out + NB * NR + NB;  // 10

    float* emb  = (float*)d_ws;        // N_PTS*DOUT floats (4 MB)
    float* part = emb + (size_t)N_PTS * DOUT; // NB*NR floats (400 KB)

    mlp_kernel<<<(N_PTS + 255) / 256, 256, 0, stream>>>(x, W1, b1, a1, W2, b2, a2, emb);
    solve_kernel<<<NB, 64, 0, stream>>>(emb, bidx, bnn, tnn, pred, var, part);
    reduce_kernel<<<1, 256, 0, stream>>>(part, sig);
}

// Round 4
// 526.295 us; speedup vs baseline: 1.9997x; 1.1225x over previous
//
#include <hip/hip_runtime.h>
#include <cstdint>

// Problem constants (match reference)
#define N_PTS 100000
#define DIN   40
#define DH    30
#define DOUT  10
#define NB    10000
#define NNB   64
#define NR    10
#define EPSF  1e-5f

__device__ __forceinline__ float fast_rcp(float x) {
    // v_rcp_f32 (~1e-7 rel err) + one Newton step -> effectively fp32-exact
    float r = __builtin_amdgcn_rcpf(x);
    r = r * (2.0f - x * r);
    return r;
}

// Broadcast lane LANE's value of x to all lanes via v_readlane_b32 -> SGPR.
// R3 lesson: __shfl lowers to ds_bpermute_b32 on the per-CU DS crossbar pipe
// (shared by 4 SIMDs) -> the solve was DS-throughput-bound at ~600us.
// readlane issues on the per-SIMD VALU pipe and its SGPR result feeds FMA
// directly (1 SGPR operand allowed per VALU instr).
__device__ __forceinline__ float lane_bcast(float x, int lane) {
    return __int_as_float(__builtin_amdgcn_readlane(__float_as_int(x), lane));
}

// ---------------------------------------------------------------------------
// Kernel 1: MLP embedding. One point per thread; weights staged in LDS.
// ---------------------------------------------------------------------------
__global__ __launch_bounds__(256) void mlp_kernel(
    const float* __restrict__ x,
    const float* __restrict__ W1, const float* __restrict__ b1, const float* __restrict__ a1p,
    const float* __restrict__ W2, const float* __restrict__ b2, const float* __restrict__ a2p,
    float* __restrict__ emb)
{
    __shared__ float sW1[DH * DIN];
    __shared__ float sW2[DOUT * DH];
    __shared__ float sb1[DH];
    __shared__ float sb2[DOUT];
    for (int i = threadIdx.x; i < DH * DIN; i += 256) sW1[i] = W1[i];
    for (int i = threadIdx.x; i < DOUT * DH; i += 256) sW2[i] = W2[i];
    if (threadIdx.x < DH)   sb1[threadIdx.x] = b1[threadIdx.x];
    if (threadIdx.x < DOUT) sb2[threadIdx.x] = b2[threadIdx.x];
    const float a1 = a1p[0], a2 = a2p[0];
    __syncthreads();

    const int n = blockIdx.x * 256 + threadIdx.x;
    if (n >= N_PTS) return;

    float xv[DIN];
    const float4* xp = reinterpret_cast<const float4*>(x + (size_t)n * DIN); // 160B rows
#pragma unroll
    for (int q = 0; q < DIN / 4; ++q) {
        float4 v = xp[q];
        xv[4*q+0] = v.x; xv[4*q+1] = v.y; xv[4*q+2] = v.z; xv[4*q+3] = v.w;
    }

    float h[DH];
#pragma unroll
    for (int i = 0; i < DH; ++i) {
        float acc = sb1[i];
#pragma unroll
        for (int j = 0; j < DIN; ++j) acc = fmaf(xv[j], sW1[i * DIN + j], acc);
        h[i] = acc > 0.0f ? acc : a1 * acc;
    }

    float* eo = emb + (size_t)n * DOUT;
#pragma unroll
    for (int d = 0; d < DOUT; ++d) {
        float acc = sb2[d];
#pragma unroll
        for (int i = 0; i < DH; ++i) acc = fmaf(h[i], sW2[d * DH + i], acc);
        eo[d] = acc > 0.0f ? acc : a2 * acc;
    }
}

// ---------------------------------------------------------------------------
// Template-recursive solve building blocks: every array index AND every
// readlane lane index is a compile-time constant (R2 lesson: runtime k ->
// scratch; R3 lesson: __shfl -> ds_bpermute -> DS-pipe bound).
// ---------------------------------------------------------------------------

// Build row `lane` of Kplus = exp(-dist) + eps*I
template<int J>
struct Build {
    static __device__ __forceinline__ void run(float (&ar)[NNB], const float (&xn)[DOUT],
                                               const float sq, const int lane) {
        float dj = 0.0f;
#pragma unroll
        for (int d = 0; d < DOUT; ++d) dj = fmaf(lane_bcast(xn[d], J), xn[d], dj);
        const float sqj = lane_bcast(sq, J);
        const float d2  = sq + sqj - 2.0f * dj;
        const float kij = __expf(-sqrtf(fmaxf(d2, 0.0f)));
        ar[J] = (J == lane) ? (1.0f + EPSF) : kij;   // exact diag + jitter
        Build<J + 1>::run(ar, xn, sq, lane);
    }
};
template<>
struct Build<NNB> {
    static __device__ __forceinline__ void run(float (&)[NNB], const float (&)[DOUT],
                                               float, int) {}
};

// Forward elimination step K (masked lanes: m=0 -> arithmetic no-op)
template<int K>
struct Fwd {
    static __device__ __forceinline__ void run(float (&ar)[NNB], float (&rr)[NR + 1],
                                               const int lane) {
        const float pd  = lane_bcast(ar[K], K);   // pivot diag (SGPR)
        const float inv = fast_rcp(pd);           // per-lane VGPR
        const float m   = (lane > K) ? ar[K] * inv : 0.0f;
#pragma unroll
        for (int j = K + 1; j < NNB; ++j)
            ar[j] = fmaf(-m, lane_bcast(ar[j], K), ar[j]);
#pragma unroll
        for (int r = 0; r <= NR; ++r)
            rr[r] = fmaf(-m, lane_bcast(rr[r], K), rr[r]);
        Fwd<K + 1>::run(ar, rr, lane);
    }
};
template<>
struct Fwd<NNB - 1> {
    static __device__ __forceinline__ void run(float (&)[NNB], float (&)[NR + 1], int) {}
};

// Back substitution step K (downward): lane K finalizes x[K], lanes i<K update
template<int K>
struct Bwd {
    static __device__ __forceinline__ void run(float (&ar)[NNB], float (&rr)[NR + 1],
                                               const int lane) {
        const float invd = fast_rcp(lane_bcast(ar[K], K));
        const float m    = (lane < K) ? ar[K] : 0.0f;    // U[lane][K]
#pragma unroll
        for (int r = 0; r <= NR; ++r) {
            const float xk = lane_bcast(rr[r], K) * invd;   // solution x[K][r]
            rr[r] = (lane == K) ? xk : fmaf(-m, xk, rr[r]);
        }
        Bwd<K - 1>::run(ar, rr, lane);
    }
};
template<>
struct Bwd<-1> {
    static __device__ __forceinline__ void run(float (&)[NNB], float (&)[NR + 1], int) {}
};

// ---------------------------------------------------------------------------
// Kernel 2: one wave per batch item, 4 items per 256-thread block.
// Row of the 64x64 system in registers; broadcasts via readlane (VALU pipe).
// __launch_bounds__(256,4): VGPR cap 128 (allocator landed exactly there in
// R3) -> 4 blocks/CU = 16 waves/CU.
// ---------------------------------------------------------------------------
__global__ __launch_bounds__(256, 4) void solve_kernel(
    const float* __restrict__ emb,
    const int* __restrict__ bidx,
    const int* __restrict__ bnn,
    const float* __restrict__ tnn_g,
    float* __restrict__ pred,   // [NB][NR]
    float* __restrict__ var,    // [NB]
    float* __restrict__ part)   // [NB][NR] sigma_sq partials
{
    const int wave = threadIdx.x >> 6;
    const int lane = threadIdx.x & 63;
    const int b    = blockIdx.x * 4 + wave;   // NB = 2500*4, exact

    // Gather this lane's neighbor embedding (10 floats, 8B-aligned rows)
    const int idx = bnn[b * NNB + lane];
    float xn[DOUT];
    {
        const float2* ep = reinterpret_cast<const float2*>(emb + (size_t)idx * DOUT);
#pragma unroll
        for (int q = 0; q < DOUT / 2; ++q) { float2 v = ep[q]; xn[2*q] = v.x; xn[2*q+1] = v.y; }
    }
    // Center embedding (same for all lanes; broadcast through cache)
    const int bi = bidx[b];
    float sq = 0.0f, dotb = 0.0f, sqb = 0.0f;
#pragma unroll
    for (int d = 0; d < DOUT; ++d) {
        const float xbd = emb[(size_t)bi * DOUT + d];
        sq   = fmaf(xn[d], xn[d], sq);
        dotb = fmaf(xbd, xn[d], dotb);
        sqb  = fmaf(xbd, xbd, sqb);
    }
    const float d2c = sqb + sq - 2.0f * dotb;
    const float kc  = __expf(-sqrtf(fmaxf(d2c, 0.0f)));

    // K matrix row (registers, static indices only)
    float ar[NNB];
    Build<0>::run(ar, xn, sq, lane);

    // RHS row: [targets(10), Kcross]. tn NOT kept live (reloaded at the end)
    // to keep peak VGPR under the 128 cap.
    float rr[NR + 1];
    {
        const float2* tp = reinterpret_cast<const float2*>(
            tnn_g + (size_t)b * NNB * NR + (size_t)lane * NR);
#pragma unroll
        for (int q = 0; q < NR / 2; ++q) { float2 v = tp[q]; rr[2*q] = v.x; rr[2*q+1] = v.y; }
    }
    rr[NR] = kc;

    Fwd<0>::run(ar, rr, lane);
    Bwd<NNB - 1>::run(ar, rr, lane);

    // Reload targets for sigma_sq partials
    float tn[NR];
    {
        const float2* tp = reinterpret_cast<const float2*>(
            tnn_g + (size_t)b * NNB * NR + (size_t)lane * NR);
#pragma unroll
        for (int q = 0; q < NR / 2; ++q) { float2 v = tp[q]; tn[2*q] = v.x; tn[2*q+1] = v.y; }
    }

    // Outputs: predictions, variance, sigma_sq partials (wave butterfly reduce)
    float pv[NR], sg[NR];
#pragma unroll
    for (int r = 0; r < NR; ++r) { pv[r] = kc * rr[r]; sg[r] = tn[r] * rr[r]; }
    float vv = kc * rr[NR];
#pragma unroll
    for (int off = 32; off > 0; off >>= 1) {
#pragma unroll
        for (int r = 0; r < NR; ++r) {
            pv[r] += __shfl_xor(pv[r], off);
            sg[r] += __shfl_xor(sg[r], off);
        }
        vv += __shfl_xor(vv, off);
    }
    if (lane == 0) {
#pragma unroll
        for (int r = 0; r < NR; ++r) {
            pred[b * NR + r] = pv[r];
            part[b * NR + r] = sg[r];
        }
        var[b] = 1.0f - vv;
    }
}

// ---------------------------------------------------------------------------
// Kernel 3: deterministic reduction of sigma_sq partials (fixed order)
// ---------------------------------------------------------------------------
__global__ __launch_bounds__(256) void reduce_kernel(
    const float* __restrict__ part, float* __restrict__ sig)
{
    float acc[NR];
#pragma unroll
    for (int r = 0; r < NR; ++r) acc[r] = 0.0f;
    for (int b = threadIdx.x; b < NB; b += 256) {
#pragma unroll
        for (int r = 0; r < NR; ++r) acc[r] += part[b * NR + r];
    }
#pragma unroll
    for (int off = 32; off > 0; off >>= 1) {
#pragma unroll
        for (int r = 0; r < NR; ++r) acc[r] += __shfl_xor(acc[r], off);
    }
    __shared__ float s[4][NR];
    const int w = threadIdx.x >> 6, l = threadIdx.x & 63;
    if (l == 0) {
#pragma unroll
        for (int r = 0; r < NR; ++r) s[w][r] = acc[r];
    }
    __syncthreads();
    if (threadIdx.x == 0) {
        const float scale = 1.0f / ((float)NB * (float)NNB);
#pragma unroll
        for (int r = 0; r < NR; ++r)
            sig[r] = (s[0][r] + s[1][r] + s[2][r] + s[3][r]) * scale;
    }
}

// ---------------------------------------------------------------------------
extern "C" void kernel_launch(void* const* d_in, const int* in_sizes, int n_in,
                              void* d_out, int out_size, void* d_ws, size_t ws_size,
                              hipStream_t stream)
{
    const float* x    = (const float*)d_in[0];
    const int*   bidx = (const int*)  d_in[1];
    const int*   bnn  = (const int*)  d_in[2];
    // d_in[3] = batch_targets: unused by the reference computation
    const float* tnn  = (const float*)d_in[4];
    const float* W1   = (const float*)d_in[5];
    const float* b1   = (const float*)d_in[6];
    const float* a1   = (const float*)d_in[7];
    const float* W2   = (const float*)d_in[8];
    const float* b2   = (const float*)d_in[9];
    const float* a2   = (const float*)d_in[10];

    float* out  = (float*)d_out;
    float* pred = out;                 // 100000
    float* var  = out + NB * NR;       // 10000
    float* sig  = out + NB * NR + NB;  // 10

    float* emb  = (float*)d_ws;        // N_PTS*DOUT floats (4 MB)
    float* part = emb + (size_t)N_PTS * DOUT; // NB*NR floats (400 KB)

    mlp_kernel<<<(N_PTS + 255) / 256, 256, 0, stream>>>(x, W1, b1, a1, W2, b2, a2, emb);
    solve_kernel<<<NB / 4, 256, 0, stream>>>(emb, bidx, bnn, tnn, pred, var, part);
    reduce_kernel<<<1, 256, 0, stream>>>(part, sig);
}

// Round 5
// 259.994 us; speedup vs baseline: 4.0478x; 2.0243x over previous
//
#include <hip/hip_runtime.h>
#include <cstdint>

// Problem constants (match reference)
#define N_PTS 100000
#define DIN   40
#define DH    30
#define DOUT  10
#define NB    10000
#define NNB   64
#define NR    10
#define EPSF  1e-5f

__device__ __forceinline__ float fast_rcp(float x) {
    // v_rcp_f32 (~1e-7 rel err) + one Newton step -> effectively fp32-exact
    float r = __builtin_amdgcn_rcpf(x);
    r = r * (2.0f - x * r);
    return r;
}

// Broadcast lane LANE's value of x to all lanes via v_readlane_b32 -> SGPR.
// R3 lesson: __shfl lowers to ds_bpermute_b32 on the per-CU DS crossbar pipe
// (shared by 4 SIMDs) -> DS-throughput-bound. readlane issues on the per-SIMD
// VALU pipe; SGPR result feeds FMA directly.
__device__ __forceinline__ float lane_bcast(float x, int lane) {
    return __int_as_float(__builtin_amdgcn_readlane(__float_as_int(x), lane));
}

// ---------------------------------------------------------------------------
// Kernel 1: MLP embedding. One point per thread; weights staged in LDS.
// ---------------------------------------------------------------------------
__global__ __launch_bounds__(256) void mlp_kernel(
    const float* __restrict__ x,
    const float* __restrict__ W1, const float* __restrict__ b1, const float* __restrict__ a1p,
    const float* __restrict__ W2, const float* __restrict__ b2, const float* __restrict__ a2p,
    float* __restrict__ emb)
{
    __shared__ float sW1[DH * DIN];
    __shared__ float sW2[DOUT * DH];
    __shared__ float sb1[DH];
    __shared__ float sb2[DOUT];
    for (int i = threadIdx.x; i < DH * DIN; i += 256) sW1[i] = W1[i];
    for (int i = threadIdx.x; i < DOUT * DH; i += 256) sW2[i] = W2[i];
    if (threadIdx.x < DH)   sb1[threadIdx.x] = b1[threadIdx.x];
    if (threadIdx.x < DOUT) sb2[threadIdx.x] = b2[threadIdx.x];
    const float a1 = a1p[0], a2 = a2p[0];
    __syncthreads();

    const int n = blockIdx.x * 256 + threadIdx.x;
    if (n >= N_PTS) return;

    float xv[DIN];
    const float4* xp = reinterpret_cast<const float4*>(x + (size_t)n * DIN); // 160B rows
#pragma unroll
    for (int q = 0; q < DIN / 4; ++q) {
        float4 v = xp[q];
        xv[4*q+0] = v.x; xv[4*q+1] = v.y; xv[4*q+2] = v.z; xv[4*q+3] = v.w;
    }

    float h[DH];
#pragma unroll
    for (int i = 0; i < DH; ++i) {
        float acc = sb1[i];
#pragma unroll
        for (int j = 0; j < DIN; ++j) acc = fmaf(xv[j], sW1[i * DIN + j], acc);
        h[i] = acc > 0.0f ? acc : a1 * acc;
    }

    float* eo = emb + (size_t)n * DOUT;
#pragma unroll
    for (int d = 0; d < DOUT; ++d) {
        float acc = sb2[d];
#pragma unroll
        for (int i = 0; i < DH; ++i) acc = fmaf(h[i], sW2[d * DH + i], acc);
        eo[d] = acc > 0.0f ? acc : a2 * acc;
    }
}

// ---------------------------------------------------------------------------
// Template-recursive solve building blocks: every array index AND every
// readlane lane index is a compile-time constant (R2: runtime k -> scratch;
// R3: __shfl -> ds_bpermute -> DS-pipe bound).
//
// R4->R5: Gauss-Jordan replaces LU fwd+bwd. At step K we eliminate column K
// from ALL rows except K (mask lane==K instead of lane>K: lanes i<K that were
// idle in plain LU now do the back-substitution work for free in SIMT).
// After 64 steps A is diagonal: x_i = rr_i / diag_i. Deletes the entire
// backward pass (~20% of instructions) and shortens ar live ranges.
// ---------------------------------------------------------------------------

// Build row `lane` of Kplus = exp(-dist) + eps*I
template<int J>
struct Build {
    static __device__ __forceinline__ void run(float (&ar)[NNB], const float (&xn)[DOUT],
                                               const float sq, const int lane) {
        float dj = 0.0f;
#pragma unroll
        for (int d = 0; d < DOUT; ++d) dj = fmaf(lane_bcast(xn[d], J), xn[d], dj);
        const float sqj = lane_bcast(sq, J);
        const float d2  = sq + sqj - 2.0f * dj;
        const float kij = __expf(-sqrtf(fmaxf(d2, 0.0f)));
        ar[J] = (J == lane) ? (1.0f + EPSF) : kij;   // exact diag + jitter
        Build<J + 1>::run(ar, xn, sq, lane);
    }
};
template<>
struct Build<NNB> {
    static __device__ __forceinline__ void run(float (&)[NNB], const float (&)[DOUT],
                                               float, int) {}
};

// Gauss-Jordan step K: eliminate column K from every row but K.
// Lane K captures its (final) diagonal via static-index cndmask.
template<int K>
struct GJ {
    static __device__ __forceinline__ void run(float (&ar)[NNB], float (&rr)[NR + 1],
                                               float& mydiag, const int lane) {
        const float pd  = lane_bcast(ar[K], K);   // pivot diag (SGPR)
        const float inv = fast_rcp(pd);
        const float m   = (lane == K) ? 0.0f : ar[K] * inv;
        mydiag = (lane == K) ? ar[K] : mydiag;    // column K never touched again
#pragma unroll
        for (int j = K + 1; j < NNB; ++j)
            ar[j] = fmaf(-m, lane_bcast(ar[j], K), ar[j]);
#pragma unroll
        for (int r = 0; r <= NR; ++r)
            rr[r] = fmaf(-m, lane_bcast(rr[r], K), rr[r]);
        GJ<K + 1>::run(ar, rr, mydiag, lane);
    }
};
template<>
struct GJ<NNB> {
    static __device__ __forceinline__ void run(float (&)[NNB], float (&)[NR + 1],
                                               float&, int) {}
};

// ---------------------------------------------------------------------------
// Kernel 2: one wave per batch item, 4 items per 256-thread block.
// Row of the 64x64 system in registers; broadcasts via readlane (VALU pipe).
// __launch_bounds__(256, 2): VGPR cap 256 -- loose enough that the allocator
// picks its preferred NO-SPILL tier (R3 showed it picks 128 given headroom;
// R4 showed a tight 128 cap makes it collapse to 64 + 208 MB of spills).
// ---------------------------------------------------------------------------
__global__ __launch_bounds__(256, 2) void solve_kernel(
    const float* __restrict__ emb,
    const int* __restrict__ bidx,
    const int* __restrict__ bnn,
    const float* __restrict__ tnn_g,
    float* __restrict__ pred,   // [NB][NR]
    float* __restrict__ var,    // [NB]
    float* __restrict__ part)   // [NB][NR] sigma_sq partials
{
    const int wave = threadIdx.x >> 6;
    const int lane = threadIdx.x & 63;
    const int b    = blockIdx.x * 4 + wave;   // NB = 2500*4, exact

    // Gather this lane's neighbor embedding (10 floats, 8B-aligned rows)
    const int idx = bnn[b * NNB + lane];
    float xn[DOUT];
    {
        const float2* ep = reinterpret_cast<const float2*>(emb + (size_t)idx * DOUT);
#pragma unroll
        for (int q = 0; q < DOUT / 2; ++q) { float2 v = ep[q]; xn[2*q] = v.x; xn[2*q+1] = v.y; }
    }
    // Center embedding (same for all lanes; broadcast through cache)
    const int bi = bidx[b];
    float sq = 0.0f, dotb = 0.0f, sqb = 0.0f;
#pragma unroll
    for (int d = 0; d < DOUT; ++d) {
        const float xbd = emb[(size_t)bi * DOUT + d];
        sq   = fmaf(xn[d], xn[d], sq);
        dotb = fmaf(xbd, xn[d], dotb);
        sqb  = fmaf(xbd, xbd, sqb);
    }
    const float d2c = sqb + sq - 2.0f * dotb;
    const float kc  = __expf(-sqrtf(fmaxf(d2c, 0.0f)));

    // K matrix row (registers, static indices only)
    float ar[NNB];
    Build<0>::run(ar, xn, sq, lane);

    // RHS row: [targets(10), Kcross]. tn NOT kept live (reloaded at the end)
    // to keep peak VGPR pressure down.
    float rr[NR + 1];
    {
        const float2* tp = reinterpret_cast<const float2*>(
            tnn_g + (size_t)b * NNB * NR + (size_t)lane * NR);
#pragma unroll
        for (int q = 0; q < NR / 2; ++q) { float2 v = tp[q]; rr[2*q] = v.x; rr[2*q+1] = v.y; }
    }
    rr[NR] = kc;

    float mydiag = 1.0f;
    GJ<0>::run(ar, rr, mydiag, lane);
    const float dinv = fast_rcp(mydiag);   // x_i = rr_i * dinv (A now diagonal)

    // Reload targets for sigma_sq partials
    float tn[NR];
    {
        const float2* tp = reinterpret_cast<const float2*>(
            tnn_g + (size_t)b * NNB * NR + (size_t)lane * NR);
#pragma unroll
        for (int q = 0; q < NR / 2; ++q) { float2 v = tp[q]; tn[2*q] = v.x; tn[2*q+1] = v.y; }
    }

    // Outputs: predictions, variance, sigma_sq partials (wave butterfly reduce)
    float pv[NR], sg[NR];
#pragma unroll
    for (int r = 0; r < NR; ++r) {
        const float xr = rr[r] * dinv;     // coeffs[lane][r]
        pv[r] = kc * xr;
        sg[r] = tn[r] * xr;
    }
    float vv = kc * rr[NR] * dinv;         // kc * kc_solve[lane]
#pragma unroll
    for (int off = 32; off > 0; off >>= 1) {
#pragma unroll
        for (int r = 0; r < NR; ++r) {
            pv[r] += __shfl_xor(pv[r], off);
            sg[r] += __shfl_xor(sg[r], off);
        }
        vv += __shfl_xor(vv, off);
    }
    if (lane == 0) {
#pragma unroll
        for (int r = 0; r < NR; ++r) {
            pred[b * NR + r] = pv[r];
            part[b * NR + r] = sg[r];
        }
        var[b] = 1.0f - vv;
    }
}

// ---------------------------------------------------------------------------
// Kernel 3: deterministic reduction of sigma_sq partials (fixed order)
// ---------------------------------------------------------------------------
__global__ __launch_bounds__(256) void reduce_kernel(
    const float* __restrict__ part, float* __restrict__ sig)
{
    float acc[NR];
#pragma unroll
    for (int r = 0; r < NR; ++r) acc[r] = 0.0f;
    for (int b = threadIdx.x; b < NB; b += 256) {
#pragma unroll
        for (int r = 0; r < NR; ++r) acc[r] += part[b * NR + r];
    }
#pragma unroll
    for (int off = 32; off > 0; off >>= 1) {
#pragma unroll
        for (int r = 0; r < NR; ++r) acc[r] += __shfl_xor(acc[r], off);
    }
    __shared__ float s[4][NR];
    const int w = threadIdx.x >> 6, l = threadIdx.x & 63;
    if (l == 0) {
#pragma unroll
        for (int r = 0; r < NR; ++r) s[w][r] = acc[r];
    }
    __syncthreads();
    if (threadIdx.x == 0) {
        const float scale = 1.0f / ((float)NB * (float)NNB);
#pragma unroll
        for (int r = 0; r < NR; ++r)
            sig[r] = (s[0][r] + s[1][r] + s[2][r] + s[3][r]) * scale;
    }
}

// ---------------------------------------------------------------------------
extern "C" void kernel_launch(void* const* d_in, const int* in_sizes, int n_in,
                              void* d_out, int out_size, void* d_ws, size_t ws_size,
                              hipStream_t stream)
{
    const float* x    = (const float*)d_in[0];
    const int*   bidx = (const int*)  d_in[1];
    const int*   bnn  = (const int*)  d_in[2];
    // d_in[3] = batch_targets: unused by the reference computation
    const float* tnn  = (const float*)d_in[4];
    const float* W1   = (const float*)d_in[5];
    const float* b1   = (const float*)d_in[6];
    const float* a1   = (const float*)d_in[7];
    const float* W2   = (const float*)d_in[8];
    const float* b2   = (const float*)d_in[9];
    const float* a2   = (const float*)d_in[10];

    float* out  = (float*)d_out;
    float* pred = out;                 // 100000
    float* var  = out + NB * NR;       // 10000
    float* sig  = out + NB * NR + NB;  // 10

    float* emb  = (float*)d_ws;        // N_PTS*DOUT floats (4 MB)
    float* part = emb + (size_t)N_PTS * DOUT; // NB*NR floats (400 KB)

    mlp_kernel<<<(N_PTS + 255) / 256, 256, 0, stream>>>(x, W1, b1, a1, W2, b2, a2, emb);
    solve_kernel<<<NB / 4, 256, 0, stream>>>(emb, bidx, bnn, tnn, pred, var, part);
    reduce_kernel<<<1, 256, 0, stream>>>(part, sig);
}

// Round 6
// 237.224 us; speedup vs baseline: 4.4364x; 1.0960x over previous
//
#include <hip/hip_runtime.h>
#include <cstdint>

// Problem constants (match reference)
#define N_PTS 100000
#define DIN   40
#define DH    30
#define DOUT  10
#define NB    10000
#define NNB   64
#define NR    10
#define EPSF  1e-5f

// Raw v_rcp_f32 (~1e-7 rel err). R5->R6: dropped the Newton step -- absmax
// headroom is 26x and the Newton chain fed every pivot (3 extra VALU ops x64).
__device__ __forceinline__ float fast_rcp(float x) {
    return __builtin_amdgcn_rcpf(x);
}

// Raw v_sqrt_f32 (no libm fixup sequence; args here are in [0, ~200], safe).
__device__ __forceinline__ float fast_sqrt(float x) {
    return __builtin_amdgcn_sqrtf(x);
}

// Broadcast lane LANE's value of x to all lanes via v_readlane_b32 -> SGPR.
// R3 lesson: __shfl lowers to ds_bpermute_b32 on the per-CU DS crossbar pipe
// (shared by 4 SIMDs) -> DS-throughput-bound. readlane issues on the per-SIMD
// VALU pipe; SGPR result feeds FMA directly.
__device__ __forceinline__ float lane_bcast(float x, int lane) {
    return __int_as_float(__builtin_amdgcn_readlane(__float_as_int(x), lane));
}

// ---------------------------------------------------------------------------
// Kernel 1: MLP embedding. One point per thread; weights staged in LDS.
// ---------------------------------------------------------------------------
__global__ __launch_bounds__(256) void mlp_kernel(
    const float* __restrict__ x,
    const float* __restrict__ W1, const float* __restrict__ b1, const float* __restrict__ a1p,
    const float* __restrict__ W2, const float* __restrict__ b2, const float* __restrict__ a2p,
    float* __restrict__ emb)
{
    __shared__ float sW1[DH * DIN];
    __shared__ float sW2[DOUT * DH];
    __shared__ float sb1[DH];
    __shared__ float sb2[DOUT];
    for (int i = threadIdx.x; i < DH * DIN; i += 256) sW1[i] = W1[i];
    for (int i = threadIdx.x; i < DOUT * DH; i += 256) sW2[i] = W2[i];
    if (threadIdx.x < DH)   sb1[threadIdx.x] = b1[threadIdx.x];
    if (threadIdx.x < DOUT) sb2[threadIdx.x] = b2[threadIdx.x];
    const float a1 = a1p[0], a2 = a2p[0];
    __syncthreads();

    const int n = blockIdx.x * 256 + threadIdx.x;
    if (n >= N_PTS) return;

    float xv[DIN];
    const float4* xp = reinterpret_cast<const float4*>(x + (size_t)n * DIN); // 160B rows
#pragma unroll
    for (int q = 0; q < DIN / 4; ++q) {
        float4 v = xp[q];
        xv[4*q+0] = v.x; xv[4*q+1] = v.y; xv[4*q+2] = v.z; xv[4*q+3] = v.w;
    }

    float h[DH];
#pragma unroll
    for (int i = 0; i < DH; ++i) {
        float acc = sb1[i];
#pragma unroll
        for (int j = 0; j < DIN; ++j) acc = fmaf(xv[j], sW1[i * DIN + j], acc);
        h[i] = acc > 0.0f ? acc : a1 * acc;
    }

    float* eo = emb + (size_t)n * DOUT;
#pragma unroll
    for (int d = 0; d < DOUT; ++d) {
        float acc = sb2[d];
#pragma unroll
        for (int i = 0; i < DH; ++i) acc = fmaf(h[i], sW2[d * DH + i], acc);
        eo[d] = acc > 0.0f ? acc : a2 * acc;
    }
}

// ---------------------------------------------------------------------------
// Template-recursive solve building blocks: every array index AND every
// readlane lane index is a compile-time constant (R2: runtime k -> scratch;
// R3: __shfl -> ds_bpermute -> DS-pipe bound).
//
// Gauss-Jordan: at step K eliminate column K from ALL rows except K (lanes
// i<K do back-substitution work for free in SIMT). After 64 steps A is
// diagonal: x_i = rr_i / diag_i. ar[j] dies at step j -> live range decays,
// peak ~85-90 floats at step 0.
// ---------------------------------------------------------------------------

// Build row `lane` of Kplus = exp(-dist) + eps*I
template<int J>
struct Build {
    static __device__ __forceinline__ void run(float (&ar)[NNB], const float (&xn)[DOUT],
                                               const float sq, const int lane) {
        float dj = 0.0f;
#pragma unroll
        for (int d = 0; d < DOUT; ++d) dj = fmaf(lane_bcast(xn[d], J), xn[d], dj);
        const float sqj = lane_bcast(sq, J);
        const float d2  = sq + sqj - 2.0f * dj;
        const float kij = __expf(-fast_sqrt(fmaxf(d2, 0.0f)));
        ar[J] = (J == lane) ? (1.0f + EPSF) : kij;   // exact diag + jitter
        Build<J + 1>::run(ar, xn, sq, lane);
    }
};
template<>
struct Build<NNB> {
    static __device__ __forceinline__ void run(float (&)[NNB], const float (&)[DOUT],
                                               float, int) {}
};

// Gauss-Jordan step K: eliminate column K from every row but K.
// Lane K captures its (final) diagonal via static-index cndmask.
template<int K>
struct GJ {
    static __device__ __forceinline__ void run(float (&ar)[NNB], float (&rr)[NR + 1],
                                               float& mydiag, const int lane) {
        const float pd  = lane_bcast(ar[K], K);   // pivot diag (SGPR)
        const float inv = fast_rcp(pd);
        const float m   = (lane == K) ? 0.0f : ar[K] * inv;
        mydiag = (lane == K) ? ar[K] : mydiag;    // column K never touched again
#pragma unroll
        for (int j = K + 1; j < NNB; ++j)
            ar[j] = fmaf(-m, lane_bcast(ar[j], K), ar[j]);
#pragma unroll
        for (int r = 0; r <= NR; ++r)
            rr[r] = fmaf(-m, lane_bcast(rr[r], K), rr[r]);
        GJ<K + 1>::run(ar, rr, mydiag, lane);
    }
};
template<>
struct GJ<NNB> {
    static __device__ __forceinline__ void run(float (&)[NNB], float (&)[NR + 1],
                                               float&, int) {}
};

// ---------------------------------------------------------------------------
// Kernel 2: one wave per batch item, 4 items per 256-thread block.
// __launch_bounds__(256, 5): min 5 waves/EU -> VGPR cap ~102/wave. GJ's true
// peak-live is ~85-90 (ar[64]+rr[11]+working; xn dead by GJ<0>; ar[j] dies at
// step j) so this fits WITHOUT spills, unlike R4's LU collapse (need>cap).
// Goal: occupancy 4->5 waves/SIMD and discourage the 52V+AGPR split that
// cost AGPR<->VGPR move traffic in R5.
// ---------------------------------------------------------------------------
__global__ __launch_bounds__(256, 5) void solve_kernel(
    const float* __restrict__ emb,
    const int* __restrict__ bidx,
    const int* __restrict__ bnn,
    const float* __restrict__ tnn_g,
    float* __restrict__ pred,   // [NB][NR]
    float* __restrict__ var,    // [NB]
    float* __restrict__ part)   // [NB][NR] sigma_sq partials
{
    const int wave = threadIdx.x >> 6;
    const int lane = threadIdx.x & 63;
    const int b    = blockIdx.x * 4 + wave;   // NB = 2500*4, exact

    // Gather this lane's neighbor embedding (10 floats, 8B-aligned rows)
    const int idx = bnn[b * NNB + lane];
    float xn[DOUT];
    {
        const float2* ep = reinterpret_cast<const float2*>(emb + (size_t)idx * DOUT);
#pragma unroll
        for (int q = 0; q < DOUT / 2; ++q) { float2 v = ep[q]; xn[2*q] = v.x; xn[2*q+1] = v.y; }
    }
    // Center embedding (same for all lanes; broadcast through cache)
    const int bi = bidx[b];
    float sq = 0.0f, dotb = 0.0f, sqb = 0.0f;
#pragma unroll
    for (int d = 0; d < DOUT; ++d) {
        const float xbd = emb[(size_t)bi * DOUT + d];
        sq   = fmaf(xn[d], xn[d], sq);
        dotb = fmaf(xbd, xn[d], dotb);
        sqb  = fmaf(xbd, xbd, sqb);
    }
    const float d2c = sqb + sq - 2.0f * dotb;
    const float kc  = __expf(-fast_sqrt(fmaxf(d2c, 0.0f)));

    // K matrix row (registers, static indices only)
    float ar[NNB];
    Build<0>::run(ar, xn, sq, lane);

    // RHS row: [targets(10), Kcross]. tn NOT kept live (reloaded at the end)
    // to keep peak VGPR pressure down.
    float rr[NR + 1];
    {
        const float2* tp = reinterpret_cast<const float2*>(
            tnn_g + (size_t)b * NNB * NR + (size_t)lane * NR);
#pragma unroll
        for (int q = 0; q < NR / 2; ++q) { float2 v = tp[q]; rr[2*q] = v.x; rr[2*q+1] = v.y; }
    }
    rr[NR] = kc;

    float mydiag = 1.0f;
    GJ<0>::run(ar, rr, mydiag, lane);
    const float dinv = fast_rcp(mydiag);   // x_i = rr_i * dinv (A now diagonal)

    // Reload targets for sigma_sq partials
    float tn[NR];
    {
        const float2* tp = reinterpret_cast<const float2*>(
            tnn_g + (size_t)b * NNB * NR + (size_t)lane * NR);
#pragma unroll
        for (int q = 0; q < NR / 2; ++q) { float2 v = tp[q]; tn[2*q] = v.x; tn[2*q+1] = v.y; }
    }

    // Outputs: predictions, variance, sigma_sq partials (wave butterfly reduce)
    float pv[NR], sg[NR];
#pragma unroll
    for (int r = 0; r < NR; ++r) {
        const float xr = rr[r] * dinv;     // coeffs[lane][r]
        pv[r] = kc * xr;
        sg[r] = tn[r] * xr;
    }
    float vv = kc * rr[NR] * dinv;         // kc * kc_solve[lane]
#pragma unroll
    for (int off = 32; off > 0; off >>= 1) {
#pragma unroll
        for (int r = 0; r < NR; ++r) {
            pv[r] += __shfl_xor(pv[r], off);
            sg[r] += __shfl_xor(sg[r], off);
        }
        vv += __shfl_xor(vv, off);
    }
    if (lane == 0) {
#pragma unroll
        for (int r = 0; r < NR; ++r) {
            pred[b * NR + r] = pv[r];
            part[b * NR + r] = sg[r];
        }
        var[b] = 1.0f - vv;
    }
}

// ---------------------------------------------------------------------------
// Kernel 3: deterministic reduction of sigma_sq partials (fixed order)
// ---------------------------------------------------------------------------
__global__ __launch_bounds__(256) void reduce_kernel(
    const float* __restrict__ part, float* __restrict__ sig)
{
    float acc[NR];
#pragma unroll
    for (int r = 0; r < NR; ++r) acc[r] = 0.0f;
    for (int b = threadIdx.x; b < NB; b += 256) {
#pragma unroll
        for (int r = 0; r < NR; ++r) acc[r] += part[b * NR + r];
    }
#pragma unroll
    for (int off = 32; off > 0; off >>= 1) {
#pragma unroll
        for (int r = 0; r < NR; ++r) acc[r] += __shfl_xor(acc[r], off);
    }
    __shared__ float s[4][NR];
    const int w = threadIdx.x >> 6, l = threadIdx.x & 63;
    if (l == 0) {
#pragma unroll
        for (int r = 0; r < NR; ++r) s[w][r] = acc[r];
    }
    __syncthreads();
    if (threadIdx.x == 0) {
        const float scale = 1.0f / ((float)NB * (float)NNB);
#pragma unroll
        for (int r = 0; r < NR; ++r)
            sig[r] = (s[0][r] + s[1][r] + s[2][r] + s[3][r]) * scale;
    }
}

// ---------------------------------------------------------------------------
extern "C" void kernel_launch(void* const* d_in, const int* in_sizes, int n_in,
                              void* d_out, int out_size, void* d_ws, size_t ws_size,
                              hipStream_t stream)
{
    const float* x    = (const float*)d_in[0];
    const int*   bidx = (const int*)  d_in[1];
    const int*   bnn  = (const int*)  d_in[2];
    // d_in[3] = batch_targets: unused by the reference computation
    const float* tnn  = (const float*)d_in[4];
    const float* W1   = (const float*)d_in[5];
    const float* b1   = (const float*)d_in[6];
    const float* a1   = (const float*)d_in[7];
    const float* W2   = (const float*)d_in[8];
    const float* b2   = (const float*)d_in[9];
    const float* a2   = (const float*)d_in[10];

    float* out  = (float*)d_out;
    float* pred = out;                 // 100000
    float* var  = out + NB * NR;       // 10000
    float* sig  = out + NB * NR + NB;  // 10

    float* emb  = (float*)d_ws;        // N_PTS*DOUT floats (4 MB)
    float* part = emb + (size_t)N_PTS * DOUT; // NB*NR floats (400 KB)

    mlp_kernel<<<(N_PTS + 255) / 256, 256, 0, stream>>>(x, W1, b1, a1, W2, b2, a2, emb);
    solve_kernel<<<NB / 4, 256, 0, stream>>>(emb, bidx, bnn, tnn, pred, var, part);
    reduce_kernel<<<1, 256, 0, stream>>>(part, sig);
}